// Round 8
// baseline (164.262 us; speedup 1.0000x reference)
//
#include <hip/hip_runtime.h>

typedef float f2 __attribute__((ext_vector_type(2)));

#define IMG 512
#define TW 32
#define TH 32
#define NG 12            // float4 col-groups per tile row: 48 cols = 32 out + 8 halo each side
#define SROW 148         // plane row stride in dwords: 96 A(f2 fp32) + 48 B(packed 2xfp16) + 4 pad
#define BOFFD 96         // B-part offset within a plane row, in dwords (384 B, 16B-aligned)
#define RROW 43          // raw halo rows: ty-5 .. ty+37
#define RS 52            // raw row stride in dwords: 48 + 4 pad; 52%4==0 keeps b128 16B-aligned,
                         //   bank-quad index (13r+g)%8 spreads 7-9 hits/quad (floor 8) per wave
#define N_TOT (16 * 3 * 512 * 512)
#define NBLK (256 * 48)  // total blocks of ssim_main
#define NSLOT 1024       // fallback atomic slots

// Gaussian(win=11, sigma=1.5), normalized, pre-doubled (SGPR-pair broadcast for pk ops).
__device__ __constant__ f2 Gw2[11] = {
    {0.00102838f, 0.00102838f}, {0.00759876f, 0.00759876f},
    {0.03600077f, 0.03600077f}, {0.10936086f, 0.10936086f},
    {0.21300537f, 0.21300537f}, {0.26601173f, 0.26601173f},
    {0.21300537f, 0.21300537f}, {0.10936086f, 0.10936086f},
    {0.03600077f, 0.03600077f}, {0.00759876f, 0.00759876f},
    {0.00102838f, 0.00102838f}};

// fp16 pack/unpack as pure-u32 inline asm (no _Float16 C-type in this TU).
// Numerics harness-verified absmax 0.0 in rounds 1-7.
__device__ __forceinline__ unsigned pkh(float a, float b) {   // (a,b) -> lo16/hi16 fp16 RTZ
    unsigned r;
    asm("v_cvt_pkrtz_f16_f32 %0, %1, %2" : "=v"(r) : "v"(a), "v"(b));
    return r;
}
__device__ __forceinline__ f2 uph(unsigned u) {               // lo16/hi16 fp16 -> (f32,f32)
    float lo, hi;
    const unsigned uh = u >> 16;
    asm("v_cvt_f32_f16 %0, %1" : "=v"(lo) : "v"(u));
    asm("v_cvt_f32_f16 %0, %1" : "=v"(hi) : "v"(uh));
    return (f2){lo, hi};
}

// Packed vertical taps for a row-pair from one input row k.
__device__ __forceinline__ void vtaps(const float4 P, const float4 T, const int k,
                                      f2 A0[4][2], f2 A1[4][2]) {
    const f2 p[2] = {{P.x, P.y}, {P.z, P.w}};
    const f2 t[2] = {{T.x, T.y}, {T.z, T.w}};
#pragma unroll
    for (int h = 0; h < 2; ++h) {
        const f2 ss = p[h] * p[h] + t[h] * t[h];
        const f2 pt = p[h] * t[h];
        if (k < 11) {                              // tap k for row r0
            const f2 w = Gw2[k];
            A0[0][h] += w * p[h];
            A0[1][h] += w * t[h];
            A0[2][h] += w * ss;
            A0[3][h] += w * pt;
        }
        if (k > 0) {                               // tap k-1 for row r0+1
            const f2 w = Gw2[k - 1];
            A1[0][h] += w * p[h];
            A1[1][h] += w * t[h];
            A1[2][h] += w * ss;
            A1[3][h] += w * pt;
        }
    }
}

// LAUNCH-BOUNDS LAW (rounds 0-6): gfx950 budgets ARCH-VGPRs = 256/min_waves_per_eu
// (half the unified 512 file). (256,8)+achievable-LDS -> cap 32 -> catastrophic spill
// (rounds 1-5, WRITE_SIZE 210 MB). (256,4) -> cap 64: round 6/7 measured VGPR 64,
// WRITE_SIZE 0.4 MB, clean. NEVER raise min_waves above 4. NEVER runtime-index
// register arrays. NEVER hand-pipeline the k-loop.
// Round-7 lesson: T1 XCD swizzle cut FETCH 141->56 MB but only -7% time; the limiter
// is phase-1's 24 serialized global-load exposures per thread -> this round stages
// the raw tile in LDS (4 independent loads/thread) and blurs from LDS.
__global__ __launch_bounds__(256, 4) void ssim_main(const float* __restrict__ pred,
                                                    const float* __restrict__ tgt,
                                                    float* __restrict__ ws,
                                                    int parts_mode) {
    // LDS: raw halo tile (p,t) + vertically-blurred plane.
    //   raw[a][r][c] : a=0 pred, a=1 tgt; 43 rows x 48 cols (+4 pad), zero-filled OOB
    //   plane A(row,c) = (vblur p, vblur t)              f2  at dword row*SROW + 2c
    //   plane B(row,c) = pkrtz(vblur p^2+t^2, vblur p*t) u32 at dword row*SROW + BOFFD + c
    // 2*43*52*4 + 32*148*4 = 17888 + 18944 -> ~36.9 KB -> 4 blocks/CU.
    __shared__ __align__(16) float raw[2][RROW][RS];
    __shared__ __align__(16) float plane[TH * SROW];
    __shared__ float red[4];

    const int tid = threadIdx.x;
    const int plane_id = blockIdx.y;         // 48 planes

    // XCD-AWARE TILE SWIZZLE (T1, round-7 verified: FETCH 141->56 MB): blockId%8 ==
    // blockIdx.x%8 selects the XCD; give each XCD a contiguous 32-tile chunk (2 tile
    // rows) per plane so halo-sharing neighbors hit the same per-XCD L2.
    const int bx = blockIdx.x;
    const int tile = ((bx & 7) << 5) | (bx >> 3);   // xcd*32 + chunk, bijective on 0..255
    const int tile_x = tile & 15;
    const int tile_y = tile >> 4;
    const int tx = tile_x * TW;
    const int ty = tile_y * TH;
    const float* pbase = pred + (size_t)plane_id * (IMG * IMG);
    const float* tbase = tgt + (size_t)plane_id * (IMG * IMG);

    // ---- Phase 0: cooperative halo-tile load, global -> LDS raw ----
    // 1032 float4 tasks = 2 arrays x 43 rows x 12 col-groups; ~4 per thread, all
    // independent -> one latency exposure. Border tiles zero-fill OOB in LDS, so
    // phase 1 needs no boundary code at all.
    {
        const bool interior = ((unsigned)(tile_x - 1) < 14u) && ((unsigned)(tile_y - 1) < 14u);
        if (interior) {
            for (int idx = tid; idx < 2 * RROW * NG; idx += 256) {
                const int arr = idx >= RROW * NG;
                const int j = idx - arr * (RROW * NG);
                const int r = j / NG;
                const int g = j - r * NG;
                const float* src = arr ? tbase : pbase;
                const float4 V = *(const float4*)(src + (ty + r - 5) * IMG + (tx + (g << 2) - 8));
                *(float4*)&raw[arr][r][g << 2] = V;
            }
        } else {
            for (int idx = tid; idx < 2 * RROW * NG; idx += 256) {
                const int arr = idx >= RROW * NG;
                const int j = idx - arr * (RROW * NG);
                const int r = j / NG;
                const int g = j - r * NG;
                const int y = ty + r - 5;
                const int x = tx + (g << 2) - 8;       // float4-aligned: all-in or all-out
                float4 V = make_float4(0.f, 0.f, 0.f, 0.f);
                if ((unsigned)y < (unsigned)IMG && (unsigned)x < (unsigned)IMG) {
                    const float* src = arr ? tbase : pbase;
                    V = *(const float4*)(src + y * IMG + x);
                }
                *(float4*)&raw[arr][r][g << 2] = V;
            }
        }
    }
    __syncthreads();

    // ---- Phase 1: vertical 11-tap blur from LDS raw, row-pair per task ----
    if (tid < NG * 16) {
        const int g4 = tid % NG;             // col group
        const int rp = tid / NG;             // row pair
        const int r0 = rp * 2;               // local output row
        const int cb = g4 << 2;              // pixel col base (col 0 == global tx-8)

        f2 A0[4][2], A1[4][2];
#pragma unroll
        for (int q = 0; q < 4; ++q)
#pragma unroll
            for (int h = 0; h < 2; ++h) { A0[q][h] = (f2)0.f; A1[q][h] = (f2)0.f; }

        // raw row for tap k of output row r0 is r0+k (ybase-ty+5 == r0). Uniform, no
        // boundary branches; ds_read_b128 pairs, compiler-scheduled.
#pragma unroll
        for (int k = 0; k < 12; ++k) {
            const float4 P = *(const float4*)&raw[0][r0 + k][cb];
            const float4 T = *(const float4*)&raw[1][r0 + k][cb];
            vtaps(P, T, k, A0, A1);
        }

        // Transpose in registers -> b128 stores. r is a compile-time unroll var.
#pragma unroll
        for (int r = 0; r < 2; ++r) {
            f2 (*A)[2] = r ? A1 : A0;
            float* rowA = &plane[(r0 + r) * SROW + (cb << 1)];
            *(float4*)rowA       = make_float4(A[0][0].x, A[1][0].x, A[0][0].y, A[1][0].y);
            *(float4*)(rowA + 4) = make_float4(A[0][1].x, A[1][1].x, A[0][1].y, A[1][1].y);
            // B: 4 pixels packed fp16x2(ss,pt) = one uint4 = one ds_write_b128.
            uint4 bv;
            bv.x = pkh(A[2][0].x, A[3][0].x);
            bv.y = pkh(A[2][0].y, A[3][0].y);
            bv.z = pkh(A[2][1].x, A[3][1].x);
            bv.w = pkh(A[2][1].y, A[3][1].y);
            *(uint4*)&plane[(r0 + r) * SROW + BOFFD + cb] = bv;
        }
    }
    __syncthreads();

    // ---- Phase 2: packed horizontal 11-tap blur + SSIM map, 4 outputs per thread ----
    // SCATTER form: each loaded pixel is consumed immediately into the <=4 outputs it
    // feeds. Peak live ~30 dwords.
    float lsum = 0.f;
    {
        const int oy = tid >> 3;             // 32 rows
        const int ox = (tid & 7) << 2;       // 8 groups of 4 output cols
        const float* rowbase = &plane[oy * SROW];

        f2 acc[4];                           // (mu1, mu2) per j
        f2 sacc[4];                          // (bss, bpt) per j
#pragma unroll
        for (int j = 0; j < 4; ++j) { acc[j] = (f2)0.f; sacc[j] = (f2)0.f; }

        // A part: load f2 cols ox+2..ox+17 (8 x b128, 16B-aligned). Pixel index i
        // (col ox+2+i) feeds output j with weight Gw2[i-1-j] when 0<=i-1-j<=10.
        {
            const float4* rowA = (const float4*)(rowbase + ((ox + 2) << 1));
#pragma unroll
            for (int i4 = 0; i4 < 8; ++i4) {
                const float4 q = rowA[i4];
                const f2 v[2] = {{q.x, q.y}, {q.z, q.w}};
#pragma unroll
                for (int h = 0; h < 2; ++h) {
                    const int i = 2 * i4 + h;
#pragma unroll
                    for (int j = 0; j < 4; ++j) {
                        const int k = i - 1 - j;
                        if (k >= 0 && k <= 10) acc[j] += Gw2[k] * v[h];
                    }
                }
            }
        }

        // B part: load packed pixels ox..ox+19 (5 x b128, contiguous span). Pixel
        // offset m (col ox+m) feeds output j with weight Gw2[m-3-j] when 0<=m-3-j<=10.
        {
            const uint4* rowB = (const uint4*)(rowbase + BOFFD + ox);
#pragma unroll
            for (int i4 = 0; i4 < 5; ++i4) {
                const uint4 q = rowB[i4];
                const unsigned qq[4] = {q.x, q.y, q.z, q.w};
#pragma unroll
                for (int c = 0; c < 4; ++c) {
                    const int m = 4 * i4 + c;
                    if (m >= 3 && m <= 16) {
                        const f2 v = uph(qq[c]);
#pragma unroll
                        for (int j = 0; j < 4; ++j) {
                            const int k = m - 3 - j;
                            if (k >= 0 && k <= 10) sacc[j] += Gw2[k] * v;
                        }
                    }
                }
            }
        }

        const float C1 = 0.0001f;            // 0.01^2
        const float C2 = 0.0009f;            // 0.03^2
#pragma unroll
        for (int j = 0; j < 4; ++j) {
            const float m1 = acc[j].x, m2 = acc[j].y;
            const float bss = sacc[j].x, bpt = sacc[j].y;
            const float mu1s = m1 * m1;
            const float mu2s = m2 * m2;
            const float mu12 = m1 * m2;
            const float A = mu1s + mu2s;
            const float s12 = bpt - mu12;    // sigma12
            const float sden = bss - A;      // sigma1^2 + sigma2^2
            const float num = fmaf(2.f, mu12, C1) * fmaf(2.f, s12, C2);
            const float den = (A + C1) * (sden + C2);
            lsum += num * __builtin_amdgcn_rcpf(den);   // rcp err ~1e-7 << 1.98e-2 threshold
        }
    }

    // ---- Reduction: wave shuffle -> LDS -> one plain store per block ----
#pragma unroll
    for (int off = 32; off > 0; off >>= 1) lsum += __shfl_down(lsum, off, 64);
    if ((tid & 63) == 0) red[tid >> 6] = lsum;
    __syncthreads();
    if (tid == 0) {
        const float bs = (red[0] + red[1]) + (red[2] + red[3]);
        const int bid = blockIdx.y * gridDim.x + blockIdx.x;
        if (parts_mode) {
            ws[bid] = bs;                    // contention-free
        } else {
            atomicAdd(&ws[bid & (NSLOT - 1)], bs);  // fallback: shallow contention
        }
    }
}

// Sum `count4` float4 partials from ws, write 1 - sum/N.
__global__ __launch_bounds__(1024) void ssim_final(const float4* __restrict__ ws4,
                                                   float* __restrict__ out, int count4) {
    __shared__ float red[16];
    const int tid = threadIdx.x;
    float s = 0.f;
    for (int i = tid; i < count4; i += 1024) {
        const float4 w = ws4[i];
        s += (w.x + w.y) + (w.z + w.w);
    }
#pragma unroll
    for (int off = 32; off > 0; off >>= 1) s += __shfl_down(s, off, 64);
    if ((tid & 63) == 0) red[tid >> 6] = s;
    __syncthreads();
    if (tid == 0) {
        float tot = 0.f;
#pragma unroll
        for (int i = 0; i < 16; ++i) tot += red[i];
        out[0] = 1.0f - tot * (1.0f / (float)N_TOT);
    }
}

extern "C" void kernel_launch(void* const* d_in, const int* in_sizes, int n_in,
                              void* d_out, int out_size, void* d_ws, size_t ws_size,
                              hipStream_t stream) {
    const float* pred = (const float*)d_in[0];
    const float* tgt = (const float*)d_in[1];
    float* out = (float*)d_out;
    float* ws = (float*)d_ws;

    const int parts_mode = (ws_size >= (size_t)NBLK * sizeof(float)) ? 1 : 0;
    if (!parts_mode) {
        hipMemsetAsync(ws, 0, NSLOT * sizeof(float), stream);
    }
    dim3 grid(256, 48);  // 16x16 tiles x (16*3) planes
    ssim_main<<<grid, 256, 0, stream>>>(pred, tgt, ws, parts_mode);
    ssim_final<<<1, 1024, 0, stream>>>((const float4*)ws, out,
                                       (parts_mode ? NBLK : NSLOT) / 4);
}